// Round 19
// baseline (56.244 us; speedup 1.0000x reference)
//
#include <hip/hip_runtime.h>
#include <hip/hip_bf16.h>
#include <hip/hip_fp16.h>

#define BATCHN 512
#define NV 50
#define NE 2450
#define INSZ 16
#define MH 32
#define NH 256

typedef short s16x8 __attribute__((ext_vector_type(8)));
typedef _Float16 f16x8 __attribute__((ext_vector_type(8)));
typedef float f32x4 __attribute__((ext_vector_type(4)));
typedef float f32x2 __attribute__((ext_vector_type(2)));

#define PRED_OFF (BATCHN * NV * INSZ)   // 409600

// ---- ws layout (bytes) ----
// W2t   f16  [3][32][32]          : 3276800 .. 3282944
// W1t   bf16 [2][3][32][32]       : 3282944 .. 3295232
// W1f   bf16 16384 (frag-major)   : 3295232 .. 3328000
// W2f   bf16 65536 (frag-major)   : 3328000 .. 3459072
// Wmuf  bf16 4096  (frag-major)   : 3459072 .. 3467264

__device__ __forceinline__ unsigned short f2bf(float x) {
  unsigned int u = __float_as_uint(x);
  unsigned int r = (u + 0x7fffu + ((u >> 16) & 1u)) >> 16;  // RTNE
  return (unsigned short)r;
}
__device__ __forceinline__ unsigned short f2h(float x) {
  return __half_as_ushort(__float2half(x));  // RTNE f32->f16
}
__device__ __forceinline__ unsigned int pk2(float a, float b) {
  return (unsigned int)f2bf(a) | ((unsigned int)f2bf(b) << 16);
}
__device__ __forceinline__ unsigned int cvtpk(float lo, float hi) {
  unsigned int r;
  asm("v_cvt_pk_bf16_f32 %0, %1, %2" : "=v"(r) : "v"(lo), "v"(hi));
  return r;
}
__device__ __forceinline__ unsigned int pkmax0(unsigned int x, unsigned int z) {
  unsigned int r;
  asm("v_pk_max_i16 %0, %1, %2" : "=v"(r) : "v"(x), "v"(z));
  return r;
}
__device__ __forceinline__ unsigned int pkaddh(unsigned int a, unsigned int b) {
  unsigned int r;
  asm("v_pk_add_f16 %0, %1, %2" : "=v"(r) : "v"(a), "v"(b));
  return r;
}
__device__ __forceinline__ void pkfma(f32x2& acc, f32x2 a, f32x2 b) {
  asm("v_pk_fma_f32 %0, %1, %2, %0" : "+v"(acc) : "v"(a), "v"(b));
}

// ---------------- Kernel 1: weight transforms -------------------
// W1f/W2f/Wmuf are FRAGMENT-MAJOR: [frag][lane][8 bf16] so a wave's B-frag
// load is one coalesced 1 KB burst. frag holds B[k][n]: n = (lane&15)+16*ntg,
// k = kc*32 + (lane>>4)*8 + e.
__global__ void k_tr(const float* __restrict__ w1, const float* __restrict__ w2,
                     const float* __restrict__ wo1, const float* __restrict__ wo2,
                     const float* __restrict__ wmu,
                     unsigned short* __restrict__ W2t, unsigned short* __restrict__ W1t,
                     unsigned short* __restrict__ W1f, unsigned short* __restrict__ W2f,
                     unsigned short* __restrict__ Wmuf) {
  int idx = blockIdx.x * 256 + threadIdx.x;
  if (idx < 3072) {                      // W2t[kk][h][c] = w2[(kk+1)*32 + c][h] (f16)
    int c = idx & 31, h = (idx >> 5) & 31, kk = idx >> 10;
    W2t[idx] = f2h(w2[((kk + 1) * 32 + c) * 32 + h]);
  } else if (idx < 9216) {               // W1t[half][kk][n][k] (bf16)
    int j = idx - 3072;
    int k = j & 31, n = (j >> 5) & 31, kk = (j >> 10) % 3, half = j / 3072;
    W1t[j] = f2bf(k < 16 ? w1[((kk + 1) * 32 + half * 16 + k) * 32 + n] : 0.f);
  } else if (idx < 9216 + 16384) {       // W1f: frag f = ntg*2 + kc (32 frags)
    int j = idx - 9216;
    int f = j >> 9, r = j & 511, lane = r >> 3, e = r & 7;
    int n = (lane & 15) + 16 * (f >> 1);
    int k = (f & 1) * 32 + ((lane >> 4) << 3) + e;
    W1f[j] = f2bf(k < 48 ? wo1[k * 256 + n] : 0.f);
  } else if (idx < 9216 + 16384 + 65536) { // W2f: frag f = ntg*8 + kc (128 frags)
    int j = idx - (9216 + 16384);
    int f = j >> 9, r = j & 511, lane = r >> 3, e = r & 7;
    int n = (lane & 15) + 16 * (f >> 3);
    int k = (f & 7) * 32 + ((lane >> 4) << 3) + e;
    W2f[j] = f2bf(wo2[k * 256 + n]);
  } else if (idx < 9216 + 16384 + 65536 + 4096) { // Wmuf: frag f = kc (8 frags)
    int j = idx - (9216 + 16384 + 65536);
    int f = j >> 9, r = j & 511, lane = r >> 3, e = r & 7;
    int n = lane & 15;
    int k = f * 32 + ((lane >> 4) << 3) + e;
    Wmuf[j] = f2bf(wmu[k * 16 + n]);
  }
}

// ---------------- Kernel 2: FUSED msg + out-MLP (one block per batch) --------
// 512 blocks x 512 thr (8 waves). Phase 1 identical to R15 (f16 hidden state).
// Phase 2: out-MLP with B-fragments read DIRECTLY from L2 in fragment-major
// layout (coalesced 1 KB bursts) -- no LDS weight staging, no WB, 8 barriers.
// LDS: S16[0,10400) R16[10400,20800) E[20800,54400); comb overlays R16;
// phase2: aug[0,9216) P1[9216,43008) agg_l[43008,49408).
__global__ void __launch_bounds__(512, 4)
k_all(const float* __restrict__ inputs, const float* __restrict__ edges,
      const float* __restrict__ b1, const float* __restrict__ b2,
      const unsigned short* __restrict__ W1t, const unsigned short* __restrict__ W2t,
      const unsigned short* __restrict__ W1f, const float* __restrict__ bo1,
      const unsigned short* __restrict__ W2f, const float* __restrict__ bo2,
      const unsigned short* __restrict__ Wmuf, const float* __restrict__ bmu,
      float* __restrict__ out) {
  __shared__ __align__(16) char smem[54400];
  unsigned short* S16 = (unsigned short*)(smem);           // [0, 10400)
  unsigned short* R16 = (unsigned short*)(smem + 10400);   // [10400, 20800)
  float* E_lds = (float*)(smem + 20800);                   // [20800, 54400)
  float* comb  = (float*)(smem + 10400);                   // overlays dead R16
  unsigned short* aug = (unsigned short*)(smem);           // phase 2
  unsigned short* P1  = (unsigned short*)(smem + 9216);    // [9216, 43008)
  float* agg_l = (float*)(smem + 43008);                   // [43008, 49408)

  const int b   = blockIdx.x;
  const int tid = threadIdx.x;
  const int w   = tid >> 6;       // 0..7
  const int l   = tid & 63;
  const int grp = l >> 4;         // 0..3
  const int lm  = l & 15;
  const int jt  = w & 3;          // receiver tile / row tile
  const int ih  = w >> 2;         // sender parity / N-half

  // ======================= PHASE 1: messages =======================
  for (int x = tid; x < NV * 56; x += 512) {
    int i  = x / 56;
    int js = x - i * 56;
    float4 ev = make_float4(0.f, 0.f, 0.f, 0.f);
    if (js < NV && js != i) {
      int e = i * 49 + js - (js > i ? 1 : 0);
      ev = reinterpret_cast<const float4*>(edges)[b * NE + e];
    }
    int base = i * 168 + js;
    E_lds[base]       = ev.y;
    E_lds[base + 56]  = ev.z;
    E_lds[base + 112] = ev.w;
  }

  // in-block fc1 GEMM: R/S = inputs @ W1 halves (K=16 zero-padded), f16 out
  {
    const int half = w >> 2;
    const int mt4  = w & 3;
    int node  = mt4 * 16 + lm;
    int nodec = node < NV ? node : NV - 1;
    s16x8 af = {0, 0, 0, 0, 0, 0, 0, 0};
    if (grp < 2) {
      const float4* ip = reinterpret_cast<const float4*>(inputs) + (b * NV + nodec) * 4 + grp * 2;
      float4 x0 = ip[0], x1 = ip[1];
      union { unsigned int u[4]; s16x8 v; } U;
      U.u[0] = cvtpk(x0.x, x0.y); U.u[1] = cvtpk(x0.z, x0.w);
      U.u[2] = cvtpk(x1.x, x1.y); U.u[3] = cvtpk(x1.z, x1.w);
      af = U.v;
    }
    unsigned short* dst = half ? S16 : R16;
#pragma unroll
    for (int kk = 0; kk < 3; ++kk) {
#pragma unroll
      for (int nt = 0; nt < 2; ++nt) {
        int h = lm + 16 * nt;
        s16x8 bf = *reinterpret_cast<const s16x8*>(W1t + ((half * 3 + kk) * 32 + h) * 32 + grp * 8);
        f32x4 C;
        if (half == 0) { float bv = b1[(kk + 1) * 32 + h]; C = f32x4{bv, bv, bv, bv}; }
        else C = f32x4{0.f, 0.f, 0.f, 0.f};
        f32x4 o = __builtin_amdgcn_mfma_f32_16x16x32_bf16(af, bf, C, 0, 0, 0);
#pragma unroll
        for (int rr = 0; rr < 4; ++rr) {
          int n2 = mt4 * 16 + grp * 4 + rr;
          if (n2 < NV) dst[n2 * 104 + kk * 32 + h] = f2h(o[rr]);
        }
      }
    }
  }

  // per-wave persistent fragments (f16 W2 B-frags + f32 bias C)
  f16x8 Bf[3][2];
  f32x4 Cb[3][2];
#pragma unroll
  for (int kk = 0; kk < 3; ++kk)
#pragma unroll
    for (int nt = 0; nt < 2; ++nt) {
      int h = lm + 16 * nt;
      Bf[kk][nt] = *reinterpret_cast<const f16x8*>(W2t + (kk * 32 + h) * 32 + grp * 8);
      float bv = b2[(kk + 1) * 32 + h];
      Cb[kk][nt] = f32x4{bv, bv, bv, bv};
    }
  __syncthreads();   // (#1)

  // Rh: this wave's 16 receiver rows in f16 (12 u32)
  unsigned int Rh[3][4];
  {
    int jrow = jt * 16 + lm;
    int jr   = jrow < NV ? jrow : NV - 1;
#pragma unroll
    for (int kk = 0; kk < 3; ++kk) {
      uint4 rv = *reinterpret_cast<const uint4*>(&R16[jr * 104 + kk * 32 + grp * 8]);
      Rh[kk][0] = rv.x; Rh[kk][1] = rv.y; Rh[kk][2] = rv.z; Rh[kk][3] = rv.w;
    }
  }
  __syncthreads();   // (#2) R16 dead (comb overlays it)

  const int slot0 = jt * 16 + grp * 4;
  const int slot  = slot0 > 52 ? 52 : slot0;   // dead lanes -> zero region

  f32x2 acc0a = {0.f, 0.f}, acc0b = {0.f, 0.f};
  f32x2 acc1a = {0.f, 0.f}, acc1b = {0.f, 0.f};

#pragma unroll 4
  for (int i = ih; i < NV; i += 2) {
    const float* Eb = &E_lds[i * 168 + slot];
#pragma unroll
    for (int kk = 0; kk < 3; ++kk) {
      uint4 sv = *reinterpret_cast<const uint4*>(&S16[i * 104 + kk * 32 + grp * 8]);
      f32x4 ev = *reinterpret_cast<const f32x4*>(Eb + kk * 56);
      union { unsigned int u[4]; f16x8 v; } U;
      U.u[0] = pkmax0(pkaddh(Rh[kk][0], sv.x), 0u);
      U.u[1] = pkmax0(pkaddh(Rh[kk][1], sv.y), 0u);
      U.u[2] = pkmax0(pkaddh(Rh[kk][2], sv.z), 0u);
      U.u[3] = pkmax0(pkaddh(Rh[kk][3], sv.w), 0u);
      f32x4 d0 = __builtin_amdgcn_mfma_f32_16x16x32_f16(U.v, Bf[kk][0], Cb[kk][0], 0, 0, 0);
      f32x4 d1 = __builtin_amdgcn_mfma_f32_16x16x32_f16(U.v, Bf[kk][1], Cb[kk][1], 0, 0, 0);
      f32x2 ea = {ev[0], ev[1]}, eb = {ev[2], ev[3]};
      f32x2 r0a = {fmaxf(d0[0], 0.f), fmaxf(d0[1], 0.f)};
      f32x2 r0b = {fmaxf(d0[2], 0.f), fmaxf(d0[3], 0.f)};
      f32x2 r1a = {fmaxf(d1[0], 0.f), fmaxf(d1[1], 0.f)};
      f32x2 r1b = {fmaxf(d1[2], 0.f), fmaxf(d1[3], 0.f)};
      pkfma(acc0a, r0a, ea); pkfma(acc0b, r0b, eb);
      pkfma(acc1a, r1a, ea); pkfma(acc1b, r1b, eb);
    }
  }

  // combine parity waves (comb overlays R16); write agg_l
  if (ih == 1) {
    int cbase = (jt * 64 + l) * 10;
    *reinterpret_cast<f32x2*>(&comb[cbase])     = acc0a;
    *reinterpret_cast<f32x2*>(&comb[cbase + 2]) = acc0b;
    *reinterpret_cast<f32x2*>(&comb[cbase + 4]) = acc1a;
    *reinterpret_cast<f32x2*>(&comb[cbase + 6]) = acc1b;
  }
  __syncthreads();   // (#3) all waves past sender loop; E dead
  if (ih == 0) {
    int cbase = (jt * 64 + l) * 10;
    acc0a += *reinterpret_cast<const f32x2*>(&comb[cbase]);
    acc0b += *reinterpret_cast<const f32x2*>(&comb[cbase + 2]);
    acc1a += *reinterpret_cast<const f32x2*>(&comb[cbase + 4]);
    acc1b += *reinterpret_cast<const f32x2*>(&comb[cbase + 6]);
    float a0v[4] = {acc0a[0], acc0a[1], acc0b[0], acc0b[1]};
    float a1v[4] = {acc1a[0], acc1a[1], acc1b[0], acc1b[1]};
#pragma unroll
    for (int rr = 0; rr < 4; ++rr) {
      int j = jt * 16 + grp * 4 + rr;
      if (j < NV) {
        agg_l[j * 32 + lm]      = a0v[rr];
        agg_l[j * 32 + 16 + lm] = a1v[rr];
      }
    }
  }
  __syncthreads();   // (#4)

  // ======================= PHASE 2: out-MLP =======================
  // aug build (waves 0-3): reads agg_l, writes aug (dead S16 region)
  if (tid < 256) {
    int row = tid >> 2, q = tid & 3;
    uint2 u0; uint4 u1;
    if (row < NV) {
      float4 iv = reinterpret_cast<const float4*>(inputs)[(b * NV + row) * 4 + q];
      u0.x = pk2(iv.x, iv.y); u0.y = pk2(iv.z, iv.w);
      f32x4 a0 = *reinterpret_cast<const f32x4*>(&agg_l[row * 32 + q * 8]);
      f32x4 a1 = *reinterpret_cast<const f32x4*>(&agg_l[row * 32 + q * 8 + 4]);
      u1.x = pk2(a0[0], a0[1]); u1.y = pk2(a0[2], a0[3]);
      u1.z = pk2(a1[0], a1[1]); u1.w = pk2(a1[2], a1[3]);
    } else { u0.x = u0.y = 0u; u1.x = u1.y = u1.z = u1.w = 0u; }
    *reinterpret_cast<uint2*>(&aug[row * 72 + q * 4]) = u0;
    *reinterpret_cast<uint4*>(&aug[row * 72 + 16 + q * 8]) = u1;
    uint2 uz; uz.x = 0u; uz.y = 0u;
    *reinterpret_cast<uint2*>(&aug[row * 72 + 48 + q * 4]) = uz;
  }
  __syncthreads();   // (#5)

  const int rowA  = 16 * jt + lm;
  const int kgrp  = grp * 8;
  const int rbase = 16 * jt + grp * 4;
  const int n0    = ih * 8;       // this wave's nt offset

  // fc1: aug[64x64] @ W1f (direct coalesced L2 frags) -> P1
  f32x4 acc1[8];
#pragma unroll
  for (int nt = 0; nt < 8; ++nt) acc1[nt] = f32x4{0.f, 0.f, 0.f, 0.f};
#pragma unroll
  for (int kc = 0; kc < 2; ++kc) {
    s16x8 af = *reinterpret_cast<const s16x8*>(&aug[rowA * 72 + kc * 32 + kgrp]);
#pragma unroll
    for (int nt = 0; nt < 8; ++nt) {
      int f = (n0 + nt) * 2 + kc;
      s16x8 bf = *reinterpret_cast<const s16x8*>(W1f + (f * 64 + l) * 8);
      acc1[nt] = __builtin_amdgcn_mfma_f32_16x16x32_bf16(af, bf, acc1[nt], 0, 0, 0);
    }
  }
#pragma unroll
  for (int nt = 0; nt < 8; ++nt) {
    int n = lm + 16 * (n0 + nt);
    float bias = bo1[n];
#pragma unroll
    for (int rr = 0; rr < 4; ++rr) {
      float v = acc1[nt][rr] + bias; v = v > 0.f ? v : 0.f;
      P1[(rbase + rr) * 264 + n] = f2bf(v);
    }
  }
  __syncthreads();   // (#6) P1 (h1) complete before fc2 reads

  // fc2: P1 @ W2f (direct coalesced L2 frags)
  f32x4 acc2[8];
#pragma unroll
  for (int nt = 0; nt < 8; ++nt) acc2[nt] = f32x4{0.f, 0.f, 0.f, 0.f};
#pragma unroll 2
  for (int kc = 0; kc < 8; ++kc) {
    s16x8 af = *reinterpret_cast<const s16x8*>(&P1[rowA * 264 + kc * 32 + kgrp]);
#pragma unroll
    for (int nt = 0; nt < 8; ++nt) {
      int f = (n0 + nt) * 8 + kc;
      s16x8 bf = *reinterpret_cast<const s16x8*>(W2f + (f * 64 + l) * 8);
      acc2[nt] = __builtin_amdgcn_mfma_f32_16x16x32_bf16(af, bf, acc2[nt], 0, 0, 0);
    }
  }
  __syncthreads();   // (#7) all fc2 reads of P1 done before rewrite

  // epilogue: write pred (f32 out, masked) + P1 bf16 (for mu)
#pragma unroll
  for (int nt = 0; nt < 8; ++nt) {
    int n = lm + 16 * (n0 + nt);
    float bias = bo2[n];
#pragma unroll
    for (int rr = 0; rr < 4; ++rr) {
      int row = rbase + rr;
      float v = acc2[nt][rr] + bias; v = v > 0.f ? v : 0.f;
      if (row < NV) out[PRED_OFF + (b * NV + row) * 256 + n] = v;
      P1[row * 264 + n] = f2bf(v);
    }
  }
  __syncthreads();   // (#8) pred bf16 complete before mu reads

  // mu: pred @ Wmuf (N-half 0 waves only)
  if (ih == 0) {
    f32x4 accm = {0.f, 0.f, 0.f, 0.f};
#pragma unroll
    for (int kc = 0; kc < 8; ++kc) {
      s16x8 af = *reinterpret_cast<const s16x8*>(&P1[rowA * 264 + kc * 32 + kgrp]);
      s16x8 bf = *reinterpret_cast<const s16x8*>(Wmuf + (kc * 64 + l) * 8);
      accm = __builtin_amdgcn_mfma_f32_16x16x32_bf16(af, bf, accm, 0, 0, 0);
    }
    float bias = bmu[lm];
#pragma unroll
    for (int rr = 0; rr < 4; ++rr) {
      int row = rbase + rr;
      if (row < NV) out[(b * NV + row) * 16 + lm] = accm[rr] + bias;
    }
  }
}

extern "C" void kernel_launch(void* const* d_in, const int* in_sizes, int n_in,
                              void* d_out, int out_size, void* d_ws, size_t ws_size,
                              hipStream_t stream) {
  const float* inputs = (const float*)d_in[0];
  const float* edges  = (const float*)d_in[1];
  const float* w1     = (const float*)d_in[2];
  const float* b1     = (const float*)d_in[3];
  const float* w2     = (const float*)d_in[4];
  const float* b2     = (const float*)d_in[5];
  const float* wo1    = (const float*)d_in[6];
  const float* bo1    = (const float*)d_in[7];
  const float* wo2    = (const float*)d_in[8];
  const float* bo2    = (const float*)d_in[9];
  const float* wmu    = (const float*)d_in[10];
  const float* bmu    = (const float*)d_in[11];
  float* out = (float*)d_out;

  char* ws = (char*)d_ws;
  unsigned short* W2t  = (unsigned short*)(ws + 3276800);
  unsigned short* W1t  = (unsigned short*)(ws + 3282944);
  unsigned short* W1f  = (unsigned short*)(ws + 3295232);
  unsigned short* W2f  = (unsigned short*)(ws + 3328000);
  unsigned short* Wmuf = (unsigned short*)(ws + 3459072);

  k_tr<<<372, 256, 0, stream>>>(w1, w2, wo1, wo2, wmu, W2t, W1t, W1f, W2f, Wmuf);
  k_all<<<512, 512, 0, stream>>>(inputs, edges, b1, b2, W1t, W2t,
                                 W1f, bo1, W2f, bo2, Wmuf, bmu, out);
}

// Round 20
// 52.164 us; speedup vs baseline: 1.0782x; 1.0782x over previous
//
#include <hip/hip_runtime.h>
#include <hip/hip_bf16.h>
#include <hip/hip_fp16.h>

#define BATCHN 512
#define NV 50
#define NE 2450
#define INSZ 16
#define MH 32
#define NH 256

typedef short s16x8 __attribute__((ext_vector_type(8)));
typedef _Float16 f16x8 __attribute__((ext_vector_type(8)));
typedef float f32x4 __attribute__((ext_vector_type(4)));
typedef float f32x2 __attribute__((ext_vector_type(2)));

#define PRED_OFF (BATCHN * NV * INSZ)   // 409600

// ---- ws layout (bytes) ----
// W2t    f16  [3][32][32]         : 3276800  .. 3282944
// W1t    bf16 [2][3][32][32]      : 3282944  .. 3295232
// Wt1sw  bf16 16384               : 3295232  .. 3328000   ([256][64] XOR-swizzled)
// Wt2sw  bf16 65536               : 3328000  .. 3459072   (4 x [256][64] swizzled)
// Wtmusw bf16 4096               : 3459072  .. 3467264   ([16][256] swizzled)

__device__ __forceinline__ unsigned short f2bf(float x) {
  unsigned int u = __float_as_uint(x);
  unsigned int r = (u + 0x7fffu + ((u >> 16) & 1u)) >> 16;  // RTNE
  return (unsigned short)r;
}
__device__ __forceinline__ unsigned short f2h(float x) {
  return __half_as_ushort(__float2half(x));  // RTNE f32->f16
}
__device__ __forceinline__ unsigned int pk2(float a, float b) {
  return (unsigned int)f2bf(a) | ((unsigned int)f2bf(b) << 16);
}
__device__ __forceinline__ unsigned int cvtpk(float lo, float hi) {
  unsigned int r;
  asm("v_cvt_pk_bf16_f32 %0, %1, %2" : "=v"(r) : "v"(lo), "v"(hi));
  return r;
}
__device__ __forceinline__ unsigned int pkmax0(unsigned int x, unsigned int z) {
  unsigned int r;
  asm("v_pk_max_i16 %0, %1, %2" : "=v"(r) : "v"(x), "v"(z));
  return r;
}
__device__ __forceinline__ unsigned int pkaddh(unsigned int a, unsigned int b) {
  unsigned int r;
  asm("v_pk_add_f16 %0, %1, %2" : "=v"(r) : "v"(a), "v"(b));
  return r;
}
__device__ __forceinline__ void pkfma(f32x2& acc, f32x2 a, f32x2 b) {
  asm("v_pk_fma_f32 %0, %1, %2, %0" : "+v"(acc) : "v"(a), "v"(b));
}

// ---------------- Kernel 1: weight transforms -------------------
__global__ void k_tr(const float* __restrict__ w1, const float* __restrict__ w2,
                     const float* __restrict__ wo1, const float* __restrict__ wo2,
                     const float* __restrict__ wmu,
                     unsigned short* __restrict__ W2t, unsigned short* __restrict__ W1t,
                     unsigned short* __restrict__ Wt1sw, unsigned short* __restrict__ Wt2sw,
                     unsigned short* __restrict__ Wtmusw) {
  int idx = blockIdx.x * 256 + threadIdx.x;
  if (idx < 3072) {                      // W2t[kk][h][c] = w2[(kk+1)*32 + c][h] (f16)
    int c = idx & 31, h = (idx >> 5) & 31, kk = idx >> 10;
    W2t[idx] = f2h(w2[((kk + 1) * 32 + c) * 32 + h]);
  } else if (idx < 9216) {               // W1t[half][kk][n][k] (bf16)
    int j = idx - 3072;
    int k = j & 31, n = (j >> 5) & 31, kk = (j >> 10) % 3, half = j / 3072;
    W1t[j] = f2bf(k < 16 ? w1[((kk + 1) * 32 + half * 16 + k) * 32 + n] : 0.f);
  } else if (idx < 9216 + 16384) {       // Wt1sw
    int j = idx - 9216; int n = j & 255, kl = j >> 8;
    float v = kl < 48 ? wo1[kl * 256 + n] : 0.f;
    Wt1sw[n * 64 + (kl ^ ((n & 7) << 3))] = f2bf(v);
  } else if (idx < 9216 + 16384 + 65536) { // Wt2sw
    int j = idx - (9216 + 16384);
    int c = j >> 14, r = j & 16383;
    int n = r & 255, kl = r >> 8;
    float v = wo2[(c * 64 + kl) * 256 + n];
    Wt2sw[(c * 256 + n) * 64 + (kl ^ ((n & 7) << 3))] = f2bf(v);
  } else if (idx < 9216 + 16384 + 65536 + 4096) { // Wtmusw
    int j = idx - (9216 + 16384 + 65536);
    int n = j & 15, kl = j >> 4;
    Wtmusw[n * 256 + (kl ^ ((n & 7) << 3))] = f2bf(wmu[kl * 16 + n]);
  }
}

// ---------------- Kernel 2: FUSED msg + out-MLP (one block per batch) --------
// 512 blocks x 512 thr (8 waves). Phase 1 = scheme-F f16 messages with a
// manual depth-1 S prefetch pipeline (f16 buffers, 2 x 12 VGPR). Phase 2 =
// R15 out-MLP (LDS-staged swizzled weights). LDS map identical to R15.
__global__ void __launch_bounds__(512, 4)
k_all(const float* __restrict__ inputs, const float* __restrict__ edges,
      const float* __restrict__ b1, const float* __restrict__ b2,
      const unsigned short* __restrict__ W1t, const unsigned short* __restrict__ W2t,
      const unsigned short* __restrict__ Wt1sw, const float* __restrict__ bo1,
      const unsigned short* __restrict__ Wt2sw, const float* __restrict__ bo2,
      const unsigned short* __restrict__ Wtmusw, const float* __restrict__ bmu,
      float* __restrict__ out) {
  __shared__ __align__(16) char smem[75776];
  unsigned short* S16 = (unsigned short*)(smem);           // [0, 10400)
  unsigned short* R16 = (unsigned short*)(smem + 10400);   // [10400, 20800)
  float* E_lds = (float*)(smem + 20800);                   // [20800, 54400)
  float* comb  = (float*)(smem + 10400);                   // overlays dead R16
  float* agg_l = (float*)(smem + 20800);                   // overlays dead E head
  unsigned short* aug = (unsigned short*)(smem);           // phase 2
  unsigned short* P1  = (unsigned short*)(smem + 9216);
  unsigned short* WB  = (unsigned short*)(smem + 43008);

  const int b   = blockIdx.x;
  const int tid = threadIdx.x;
  const int w   = tid >> 6;       // 0..7
  const int l   = tid & 63;
  const int grp = l >> 4;         // 0..3
  const int lm  = l & 15;
  const int jt  = w & 3;          // receiver tile / row tile
  const int ih  = w >> 2;         // sender parity / N-half

  // ======================= PHASE 1: messages =======================
  // stage E: E_lds[i][kk][js]; js >= 50 and diagonal = 0
  for (int x = tid; x < NV * 56; x += 512) {
    int i  = x / 56;
    int js = x - i * 56;
    float4 ev = make_float4(0.f, 0.f, 0.f, 0.f);
    if (js < NV && js != i) {
      int e = i * 49 + js - (js > i ? 1 : 0);
      ev = reinterpret_cast<const float4*>(edges)[b * NE + e];
    }
    int base = i * 168 + js;
    E_lds[base]       = ev.y;
    E_lds[base + 56]  = ev.z;
    E_lds[base + 112] = ev.w;
  }

  // in-block fc1 GEMM: R/S = inputs @ W1 halves (K=16 zero-padded), f16 out
  {
    const int half = w >> 2;
    const int mt4  = w & 3;
    int node  = mt4 * 16 + lm;
    int nodec = node < NV ? node : NV - 1;
    s16x8 af = {0, 0, 0, 0, 0, 0, 0, 0};
    if (grp < 2) {
      const float4* ip = reinterpret_cast<const float4*>(inputs) + (b * NV + nodec) * 4 + grp * 2;
      float4 x0 = ip[0], x1 = ip[1];
      union { unsigned int u[4]; s16x8 v; } U;
      U.u[0] = cvtpk(x0.x, x0.y); U.u[1] = cvtpk(x0.z, x0.w);
      U.u[2] = cvtpk(x1.x, x1.y); U.u[3] = cvtpk(x1.z, x1.w);
      af = U.v;
    }
    unsigned short* dst = half ? S16 : R16;
#pragma unroll
    for (int kk = 0; kk < 3; ++kk) {
#pragma unroll
      for (int nt = 0; nt < 2; ++nt) {
        int h = lm + 16 * nt;
        s16x8 bf = *reinterpret_cast<const s16x8*>(W1t + ((half * 3 + kk) * 32 + h) * 32 + grp * 8);
        f32x4 C;
        if (half == 0) { float bv = b1[(kk + 1) * 32 + h]; C = f32x4{bv, bv, bv, bv}; }
        else C = f32x4{0.f, 0.f, 0.f, 0.f};
        f32x4 o = __builtin_amdgcn_mfma_f32_16x16x32_bf16(af, bf, C, 0, 0, 0);
#pragma unroll
        for (int rr = 0; rr < 4; ++rr) {
          int n2 = mt4 * 16 + grp * 4 + rr;
          if (n2 < NV) dst[n2 * 104 + kk * 32 + h] = f2h(o[rr]);
        }
      }
    }
  }

  // per-wave persistent fragments (f16 W2 B-frags + f32 bias C)
  f16x8 Bf[3][2];
  f32x4 Cb[3][2];
#pragma unroll
  for (int kk = 0; kk < 3; ++kk)
#pragma unroll
    for (int nt = 0; nt < 2; ++nt) {
      int h = lm + 16 * nt;
      Bf[kk][nt] = *reinterpret_cast<const f16x8*>(W2t + (kk * 32 + h) * 32 + grp * 8);
      float bv = b2[(kk + 1) * 32 + h];
      Cb[kk][nt] = f32x4{bv, bv, bv, bv};
    }
  __syncthreads();

  // Rh: this wave's 16 receiver rows in f16 (12 u32)
  unsigned int Rh[3][4];
  {
    int jrow = jt * 16 + lm;
    int jr   = jrow < NV ? jrow : NV - 1;
#pragma unroll
    for (int kk = 0; kk < 3; ++kk) {
      uint4 rv = *reinterpret_cast<const uint4*>(&R16[jr * 104 + kk * 32 + grp * 8]);
      Rh[kk][0] = rv.x; Rh[kk][1] = rv.y; Rh[kk][2] = rv.z; Rh[kk][3] = rv.w;
    }
  }
  __syncthreads();   // R16 dead (comb overlays it)

  const int slot0 = jt * 16 + grp * 4;
  const int slot  = slot0 > 52 ? 52 : slot0;   // dead lanes -> zero region (50..55)

  f32x2 acc0a = {0.f, 0.f}, acc0b = {0.f, 0.f};
  f32x2 acc1a = {0.f, 0.f}, acc1b = {0.f, 0.f};

  // ---- manual depth-1 S prefetch pipeline (f16: 3 uint4 per buffer) ----
  auto LOADS = [&](int i, uint4 (&sv)[3]) {
#pragma unroll
    for (int kk = 0; kk < 3; ++kk)
      sv[kk] = *reinterpret_cast<const uint4*>(&S16[i * 104 + kk * 32 + grp * 8]);
  };
  auto COMPI = [&](int i, const uint4 (&sv)[3]) {
    const float* Eb = &E_lds[i * 168 + slot];
#pragma unroll
    for (int kk = 0; kk < 3; ++kk) {
      f32x4 ev = *reinterpret_cast<const f32x4*>(Eb + kk * 56);
      union { unsigned int u[4]; f16x8 v; } U;
      U.u[0] = pkmax0(pkaddh(Rh[kk][0], sv[kk].x), 0u);
      U.u[1] = pkmax0(pkaddh(Rh[kk][1], sv[kk].y), 0u);
      U.u[2] = pkmax0(pkaddh(Rh[kk][2], sv[kk].z), 0u);
      U.u[3] = pkmax0(pkaddh(Rh[kk][3], sv[kk].w), 0u);
      f32x4 d0 = __builtin_amdgcn_mfma_f32_16x16x32_f16(U.v, Bf[kk][0], Cb[kk][0], 0, 0, 0);
      f32x4 d1 = __builtin_amdgcn_mfma_f32_16x16x32_f16(U.v, Bf[kk][1], Cb[kk][1], 0, 0, 0);
      f32x2 ea = {ev[0], ev[1]}, eb = {ev[2], ev[3]};
      f32x2 r0a = {fmaxf(d0[0], 0.f), fmaxf(d0[1], 0.f)};
      f32x2 r0b = {fmaxf(d0[2], 0.f), fmaxf(d0[3], 0.f)};
      f32x2 r1a = {fmaxf(d1[0], 0.f), fmaxf(d1[1], 0.f)};
      f32x2 r1b = {fmaxf(d1[2], 0.f), fmaxf(d1[3], 0.f)};
      pkfma(acc0a, r0a, ea); pkfma(acc0b, r0b, eb);
      pkfma(acc1a, r1a, ea); pkfma(acc1b, r1b, eb);
    }
  };

  {
    uint4 svA[3], svB[3];
    LOADS(ih, svA);                       // t = 0
    for (int t = 0; t < 12; ++t) {        // handles t = 0..23
      LOADS(ih + 2 * (2 * t + 1), svB);
      COMPI(ih + 2 * (2 * t), svA);
      LOADS(ih + 2 * (2 * t + 2), svA);
      COMPI(ih + 2 * (2 * t + 1), svB);
    }
    COMPI(ih + 48, svA);                  // t = 24
  }

  // combine parity waves; write agg into LDS
  if (ih == 1) {
    int cbase = (jt * 64 + l) * 10;
    *reinterpret_cast<f32x2*>(&comb[cbase])     = acc0a;
    *reinterpret_cast<f32x2*>(&comb[cbase + 2]) = acc0b;
    *reinterpret_cast<f32x2*>(&comb[cbase + 4]) = acc1a;
    *reinterpret_cast<f32x2*>(&comb[cbase + 6]) = acc1b;
  }
  __syncthreads();
  if (ih == 0) {
    int cbase = (jt * 64 + l) * 10;
    acc0a += *reinterpret_cast<const f32x2*>(&comb[cbase]);
    acc0b += *reinterpret_cast<const f32x2*>(&comb[cbase + 2]);
    acc1a += *reinterpret_cast<const f32x2*>(&comb[cbase + 4]);
    acc1b += *reinterpret_cast<const f32x2*>(&comb[cbase + 6]);
    float a0v[4] = {acc0a[0], acc0a[1], acc0b[0], acc0b[1]};
    float a1v[4] = {acc1a[0], acc1a[1], acc1b[0], acc1b[1]};
#pragma unroll
    for (int rr = 0; rr < 4; ++rr) {
      int j = jt * 16 + grp * 4 + rr;
      if (j < NV) {
        agg_l[j * 32 + lm]      = a0v[rr];
        agg_l[j * 32 + 16 + lm] = a1v[rr];
      }
    }
  }
  __syncthreads();

  // ======================= PHASE 2: out-MLP =======================
  const int xo = (lm & 7) << 3;

  // aug build (waves 0-3) + stage Wt1sw (all)
  if (tid < 256) {
    int row = tid >> 2, q = tid & 3;
    uint2 u0; uint4 u1;
    if (row < NV) {
      float4 iv = reinterpret_cast<const float4*>(inputs)[(b * NV + row) * 4 + q];
      u0.x = pk2(iv.x, iv.y); u0.y = pk2(iv.z, iv.w);
      f32x4 a0 = *reinterpret_cast<const f32x4*>(&agg_l[row * 32 + q * 8]);
      f32x4 a1 = *reinterpret_cast<const f32x4*>(&agg_l[row * 32 + q * 8 + 4]);
      u1.x = pk2(a0[0], a0[1]); u1.y = pk2(a0[2], a0[3]);
      u1.z = pk2(a1[0], a1[1]); u1.w = pk2(a1[2], a1[3]);
    } else { u0.x = u0.y = 0u; u1.x = u1.y = u1.z = u1.w = 0u; }
    *reinterpret_cast<uint2*>(&aug[row * 72 + q * 4]) = u0;
    *reinterpret_cast<uint4*>(&aug[row * 72 + 16 + q * 8]) = u1;
    uint2 uz; uz.x = 0u; uz.y = 0u;
    *reinterpret_cast<uint2*>(&aug[row * 72 + 48 + q * 4]) = uz;
  }
  {
    const uint4* src = reinterpret_cast<const uint4*>(Wt1sw);
    for (int i2 = tid; i2 < 2048; i2 += 512) reinterpret_cast<uint4*>(WB)[i2] = src[i2];
  }
  __syncthreads();

  const int rowA  = 16 * jt + lm;
  const int kgrp  = grp * 8;
  const int rbase = 16 * jt + grp * 4;
  const int n0    = ih * 8;       // this wave's nt offset

  // fc1: aug[64x64] @ Wt1 -> P1
  f32x4 acc1[8];
#pragma unroll
  for (int nt = 0; nt < 8; ++nt) acc1[nt] = f32x4{0.f, 0.f, 0.f, 0.f};
#pragma unroll
  for (int kc = 0; kc < 2; ++kc) {
    s16x8 af = *reinterpret_cast<const s16x8*>(&aug[rowA * 72 + kc * 32 + kgrp]);
#pragma unroll
    for (int nt = 0; nt < 8; ++nt) {
      int n = lm + 16 * (n0 + nt);
      s16x8 bf = *reinterpret_cast<const s16x8*>(&WB[n * 64 + ((kc * 32 + kgrp) ^ xo)]);
      acc1[nt] = __builtin_amdgcn_mfma_f32_16x16x32_bf16(af, bf, acc1[nt], 0, 0, 0);
    }
  }
#pragma unroll
  for (int nt = 0; nt < 8; ++nt) {
    int n = lm + 16 * (n0 + nt);
    float bias = bo1[n];
#pragma unroll
    for (int rr = 0; rr < 4; ++rr) {
      float v = acc1[nt][rr] + bias; v = v > 0.f ? v : 0.f;
      P1[(rbase + rr) * 264 + n] = f2bf(v);
    }
  }
  __syncthreads();   // WB (Wt1) readers + P1 writers done

  // fc2: P1 @ Wt2 (4 staged chunks)
  f32x4 acc2[8];
#pragma unroll
  for (int nt = 0; nt < 8; ++nt) acc2[nt] = f32x4{0.f, 0.f, 0.f, 0.f};
  for (int c = 0; c < 4; ++c) {
    const uint4* src = reinterpret_cast<const uint4*>(Wt2sw + c * 16384);
    for (int i2 = tid; i2 < 2048; i2 += 512) reinterpret_cast<uint4*>(WB)[i2] = src[i2];
    __syncthreads();
#pragma unroll
    for (int kcl = 0; kcl < 2; ++kcl) {
      int kc = c * 2 + kcl;
      s16x8 af = *reinterpret_cast<const s16x8*>(&P1[rowA * 264 + kc * 32 + kgrp]);
#pragma unroll
      for (int nt = 0; nt < 8; ++nt) {
        int n = lm + 16 * (n0 + nt);
        s16x8 bf = *reinterpret_cast<const s16x8*>(&WB[n * 64 + ((kcl * 32 + kgrp) ^ xo)]);
        acc2[nt] = __builtin_amdgcn_mfma_f32_16x16x32_bf16(af, bf, acc2[nt], 0, 0, 0);
      }
    }
    __syncthreads();
  }
  // epilogue: write pred (f32 out, masked) + P1 bf16 (for mu)
#pragma unroll
  for (int nt = 0; nt < 8; ++nt) {
    int n = lm + 16 * (n0 + nt);
    float bias = bo2[n];
#pragma unroll
    for (int rr = 0; rr < 4; ++rr) {
      int row = rbase + rr;
      float v = acc2[nt][rr] + bias; v = v > 0.f ? v : 0.f;
      if (row < NV) out[PRED_OFF + (b * NV + row) * 256 + n] = v;
      P1[row * 264 + n] = f2bf(v);
    }
  }
  // stage Wtmusw (512 uint4 = one per thread)
  reinterpret_cast<uint4*>(WB)[tid] = reinterpret_cast<const uint4*>(Wtmusw)[tid];
  __syncthreads();

  // mu: pred @ Wtmu (N-half 0 waves only)
  if (ih == 0) {
    f32x4 accm = {0.f, 0.f, 0.f, 0.f};
#pragma unroll
    for (int kc = 0; kc < 8; ++kc) {
      s16x8 af = *reinterpret_cast<const s16x8*>(&P1[rowA * 264 + kc * 32 + kgrp]);
      s16x8 bf = *reinterpret_cast<const s16x8*>(&WB[lm * 256 + ((kc * 32 + kgrp) ^ xo)]);
      accm = __builtin_amdgcn_mfma_f32_16x16x32_bf16(af, bf, accm, 0, 0, 0);
    }
    float bias = bmu[lm];
#pragma unroll
    for (int rr = 0; rr < 4; ++rr) {
      int row = rbase + rr;
      if (row < NV) out[(b * NV + row) * 16 + lm] = accm[rr] + bias;
    }
  }
}

extern "C" void kernel_launch(void* const* d_in, const int* in_sizes, int n_in,
                              void* d_out, int out_size, void* d_ws, size_t ws_size,
                              hipStream_t stream) {
  const float* inputs = (const float*)d_in[0];
  const float* edges  = (const float*)d_in[1];
  const float* w1     = (const float*)d_in[2];
  const float* b1     = (const float*)d_in[3];
  const float* w2     = (const float*)d_in[4];
  const float* b2     = (const float*)d_in[5];
  const float* wo1    = (const float*)d_in[6];
  const float* bo1    = (const float*)d_in[7];
  const float* wo2    = (const float*)d_in[8];
  const float* bo2    = (const float*)d_in[9];
  const float* wmu    = (const float*)d_in[10];
  const float* bmu    = (const float*)d_in[11];
  float* out = (float*)d_out;

  char* ws = (char*)d_ws;
  unsigned short* W2t    = (unsigned short*)(ws + 3276800);
  unsigned short* W1t    = (unsigned short*)(ws + 3282944);
  unsigned short* Wt1sw  = (unsigned short*)(ws + 3295232);
  unsigned short* Wt2sw  = (unsigned short*)(ws + 3328000);
  unsigned short* Wtmusw = (unsigned short*)(ws + 3459072);

  k_tr<<<372, 256, 0, stream>>>(w1, w2, wo1, wo2, wmu, W2t, W1t, Wt1sw, Wt2sw, Wtmusw);
  k_all<<<512, 512, 0, stream>>>(inputs, edges, b1, b2, W1t, W2t,
                                 Wt1sw, bo1, Wt2sw, bo2, Wtmusw, bmu, out);
}

// Round 21
// 49.350 us; speedup vs baseline: 1.1397x; 1.0570x over previous
//
#include <hip/hip_runtime.h>
#include <hip/hip_bf16.h>
#include <hip/hip_fp16.h>

#define BATCHN 512
#define NV 50
#define NE 2450
#define INSZ 16
#define MH 32
#define NH 256

typedef short s16x8 __attribute__((ext_vector_type(8)));
typedef _Float16 f16x8 __attribute__((ext_vector_type(8)));
typedef float f32x4 __attribute__((ext_vector_type(4)));
typedef float f32x2 __attribute__((ext_vector_type(2)));

#define PRED_OFF (BATCHN * NV * INSZ)   // 409600

// ---- ws layout (bytes) ----
// W2t    f16  [3][32][32]         : 3276800  .. 3282944
// W1t    bf16 [2][3][32][32]      : 3282944  .. 3295232
// Wt1sw  bf16 16384               : 3295232  .. 3328000
// Wt2sw  bf16 65536               : 3328000  .. 3459072
// Wtmusw bf16 4096                : 3459072  .. 3467264

__device__ __forceinline__ unsigned short f2bf(float x) {
  unsigned int u = __float_as_uint(x);
  unsigned int r = (u + 0x7fffu + ((u >> 16) & 1u)) >> 16;  // RTNE
  return (unsigned short)r;
}
__device__ __forceinline__ unsigned short f2h(float x) {
  return __half_as_ushort(__float2half(x));  // RTNE f32->f16
}
__device__ __forceinline__ unsigned int pk2(float a, float b) {
  return (unsigned int)f2bf(a) | ((unsigned int)f2bf(b) << 16);
}
__device__ __forceinline__ unsigned int cvtpk(float lo, float hi) {
  unsigned int r;
  asm("v_cvt_pk_bf16_f32 %0, %1, %2" : "=v"(r) : "v"(lo), "v"(hi));
  return r;
}
__device__ __forceinline__ unsigned int pkmax0(unsigned int x, unsigned int z) {
  unsigned int r;
  asm("v_pk_max_i16 %0, %1, %2" : "=v"(r) : "v"(x), "v"(z));
  return r;
}
__device__ __forceinline__ unsigned int pkaddh(unsigned int a, unsigned int b) {
  unsigned int r;
  asm("v_pk_add_f16 %0, %1, %2" : "=v"(r) : "v"(a), "v"(b));
  return r;
}
__device__ __forceinline__ void pkfma(f32x2& acc, f32x2 a, f32x2 b) {
  asm("v_pk_fma_f32 %0, %1, %2, %0" : "+v"(acc) : "v"(a), "v"(b));
}

// ---------------- Kernel 1: weight transforms -------------------
__global__ void k_tr(const float* __restrict__ w1, const float* __restrict__ w2,
                     const float* __restrict__ wo1, const float* __restrict__ wo2,
                     const float* __restrict__ wmu,
                     unsigned short* __restrict__ W2t, unsigned short* __restrict__ W1t,
                     unsigned short* __restrict__ Wt1sw, unsigned short* __restrict__ Wt2sw,
                     unsigned short* __restrict__ Wtmusw) {
  int idx = blockIdx.x * 256 + threadIdx.x;
  if (idx < 3072) {                      // W2t[kk][h][c] = w2[(kk+1)*32 + c][h] (f16)
    int c = idx & 31, h = (idx >> 5) & 31, kk = idx >> 10;
    W2t[idx] = f2h(w2[((kk + 1) * 32 + c) * 32 + h]);
  } else if (idx < 9216) {               // W1t[half][kk][n][k] (bf16)
    int j = idx - 3072;
    int k = j & 31, n = (j >> 5) & 31, kk = (j >> 10) % 3, half = j / 3072;
    W1t[j] = f2bf(k < 16 ? w1[((kk + 1) * 32 + half * 16 + k) * 32 + n] : 0.f);
  } else if (idx < 9216 + 16384) {       // Wt1sw
    int j = idx - 9216; int n = j & 255, kl = j >> 8;
    float v = kl < 48 ? wo1[kl * 256 + n] : 0.f;
    Wt1sw[n * 64 + (kl ^ ((n & 7) << 3))] = f2bf(v);
  } else if (idx < 9216 + 16384 + 65536) { // Wt2sw
    int j = idx - (9216 + 16384);
    int c = j >> 14, r = j & 16383;
    int n = r & 255, kl = r >> 8;
    float v = wo2[(c * 64 + kl) * 256 + n];
    Wt2sw[(c * 256 + n) * 64 + (kl ^ ((n & 7) << 3))] = f2bf(v);
  } else if (idx < 9216 + 16384 + 65536 + 4096) { // Wtmusw
    int j = idx - (9216 + 16384 + 65536);
    int n = j & 15, kl = j >> 4;
    Wtmusw[n * 256 + (kl ^ ((n & 7) << 3))] = f2bf(wmu[kl * 16 + n]);
  }
}

// ---------------- Kernel 2: FUSED msg + out-MLP (one block per batch) --------
// 512 blocks x 512 thr (8 waves). Phase 1 = scheme-F messages with f16 hidden
// state: S,R stored f16 in LDS (1 b128 per (i,kk) S-read), A = relu(R+S) via
// v_pk_add_f16 + v_pk_max_i16 (8 VALU, no converts), MFMA 16x16x32_f16.
// E stays f32 [i][kk][56] with zero region at slots >= 50. Phase 2 = out-MLP.
// LDS map: S16[0,10400) R16[10400,20800) E[20800,54400); comb overlays R16;
// agg_l overlays E head; phase2 aug[0,9216) P1[9216,43008) WB[43008,75776).
__global__ void __launch_bounds__(512, 4)
k_all(const float* __restrict__ inputs, const float* __restrict__ edges,
      const float* __restrict__ b1, const float* __restrict__ b2,
      const unsigned short* __restrict__ W1t, const unsigned short* __restrict__ W2t,
      const unsigned short* __restrict__ Wt1sw, const float* __restrict__ bo1,
      const unsigned short* __restrict__ Wt2sw, const float* __restrict__ bo2,
      const unsigned short* __restrict__ Wtmusw, const float* __restrict__ bmu,
      float* __restrict__ out) {
  __shared__ __align__(16) char smem[75776];
  unsigned short* S16 = (unsigned short*)(smem);           // [0, 10400)
  unsigned short* R16 = (unsigned short*)(smem + 10400);   // [10400, 20800)
  float* E_lds = (float*)(smem + 20800);                   // [20800, 54400)
  float* comb  = (float*)(smem + 10400);                   // overlays dead R16
  float* agg_l = (float*)(smem + 20800);                   // overlays dead E head
  unsigned short* aug = (unsigned short*)(smem);           // phase 2
  unsigned short* P1  = (unsigned short*)(smem + 9216);
  unsigned short* WB  = (unsigned short*)(smem + 43008);

  const int b   = blockIdx.x;
  const int tid = threadIdx.x;
  const int w   = tid >> 6;       // 0..7
  const int l   = tid & 63;
  const int grp = l >> 4;         // 0..3
  const int lm  = l & 15;
  const int jt  = w & 3;          // receiver tile / row tile
  const int ih  = w >> 2;         // sender parity / N-half

  // ======================= PHASE 1: messages =======================
  // stage E: E_lds[i][kk][js]; js >= 50 and diagonal = 0
  for (int x = tid; x < NV * 56; x += 512) {
    int i  = x / 56;
    int js = x - i * 56;
    float4 ev = make_float4(0.f, 0.f, 0.f, 0.f);
    if (js < NV && js != i) {
      int e = i * 49 + js - (js > i ? 1 : 0);
      ev = reinterpret_cast<const float4*>(edges)[b * NE + e];
    }
    int base = i * 168 + js;
    E_lds[base]       = ev.y;
    E_lds[base + 56]  = ev.z;
    E_lds[base + 112] = ev.w;
  }

  // in-block fc1 GEMM: R/S = inputs @ W1 halves (K=16 zero-padded), f16 out
  {
    const int half = w >> 2;
    const int mt4  = w & 3;
    int node  = mt4 * 16 + lm;
    int nodec = node < NV ? node : NV - 1;
    s16x8 af = {0, 0, 0, 0, 0, 0, 0, 0};
    if (grp < 2) {
      const float4* ip = reinterpret_cast<const float4*>(inputs) + (b * NV + nodec) * 4 + grp * 2;
      float4 x0 = ip[0], x1 = ip[1];
      union { unsigned int u[4]; s16x8 v; } U;
      U.u[0] = cvtpk(x0.x, x0.y); U.u[1] = cvtpk(x0.z, x0.w);
      U.u[2] = cvtpk(x1.x, x1.y); U.u[3] = cvtpk(x1.z, x1.w);
      af = U.v;
    }
    unsigned short* dst = half ? S16 : R16;
#pragma unroll
    for (int kk = 0; kk < 3; ++kk) {
#pragma unroll
      for (int nt = 0; nt < 2; ++nt) {
        int h = lm + 16 * nt;
        s16x8 bf = *reinterpret_cast<const s16x8*>(W1t + ((half * 3 + kk) * 32 + h) * 32 + grp * 8);
        f32x4 C;
        if (half == 0) { float bv = b1[(kk + 1) * 32 + h]; C = f32x4{bv, bv, bv, bv}; }
        else C = f32x4{0.f, 0.f, 0.f, 0.f};
        f32x4 o = __builtin_amdgcn_mfma_f32_16x16x32_bf16(af, bf, C, 0, 0, 0);
#pragma unroll
        for (int rr = 0; rr < 4; ++rr) {
          int n2 = mt4 * 16 + grp * 4 + rr;
          if (n2 < NV) dst[n2 * 104 + kk * 32 + h] = f2h(o[rr]);
        }
      }
    }
  }

  // per-wave persistent fragments (f16 W2 B-frags + f32 bias C)
  f16x8 Bf[3][2];
  f32x4 Cb[3][2];
#pragma unroll
  for (int kk = 0; kk < 3; ++kk)
#pragma unroll
    for (int nt = 0; nt < 2; ++nt) {
      int h = lm + 16 * nt;
      Bf[kk][nt] = *reinterpret_cast<const f16x8*>(W2t + (kk * 32 + h) * 32 + grp * 8);
      float bv = b2[(kk + 1) * 32 + h];
      Cb[kk][nt] = f32x4{bv, bv, bv, bv};
    }
  __syncthreads();

  // Rh: this wave's 16 receiver rows in f16 (12 u32)
  unsigned int Rh[3][4];
  {
    int jrow = jt * 16 + lm;
    int jr   = jrow < NV ? jrow : NV - 1;
#pragma unroll
    for (int kk = 0; kk < 3; ++kk) {
      uint4 rv = *reinterpret_cast<const uint4*>(&R16[jr * 104 + kk * 32 + grp * 8]);
      Rh[kk][0] = rv.x; Rh[kk][1] = rv.y; Rh[kk][2] = rv.z; Rh[kk][3] = rv.w;
    }
  }
  __syncthreads();   // R16 dead (comb overlays it)

  const int slot0 = jt * 16 + grp * 4;
  const int slot  = slot0 > 52 ? 52 : slot0;   // dead lanes -> zero region (50..55)

  f32x2 acc0a = {0.f, 0.f}, acc0b = {0.f, 0.f};
  f32x2 acc1a = {0.f, 0.f}, acc1b = {0.f, 0.f};

#pragma unroll 4
  for (int i = ih; i < NV; i += 2) {
    const float* Eb = &E_lds[i * 168 + slot];
#pragma unroll
    for (int kk = 0; kk < 3; ++kk) {
      uint4 sv = *reinterpret_cast<const uint4*>(&S16[i * 104 + kk * 32 + grp * 8]);
      f32x4 ev = *reinterpret_cast<const f32x4*>(Eb + kk * 56);
      union { unsigned int u[4]; f16x8 v; } U;
      U.u[0] = pkmax0(pkaddh(Rh[kk][0], sv.x), 0u);
      U.u[1] = pkmax0(pkaddh(Rh[kk][1], sv.y), 0u);
      U.u[2] = pkmax0(pkaddh(Rh[kk][2], sv.z), 0u);
      U.u[3] = pkmax0(pkaddh(Rh[kk][3], sv.w), 0u);
      f32x4 d0 = __builtin_amdgcn_mfma_f32_16x16x32_f16(U.v, Bf[kk][0], Cb[kk][0], 0, 0, 0);
      f32x4 d1 = __builtin_amdgcn_mfma_f32_16x16x32_f16(U.v, Bf[kk][1], Cb[kk][1], 0, 0, 0);
      f32x2 ea = {ev[0], ev[1]}, eb = {ev[2], ev[3]};
      f32x2 r0a = {fmaxf(d0[0], 0.f), fmaxf(d0[1], 0.f)};
      f32x2 r0b = {fmaxf(d0[2], 0.f), fmaxf(d0[3], 0.f)};
      f32x2 r1a = {fmaxf(d1[0], 0.f), fmaxf(d1[1], 0.f)};
      f32x2 r1b = {fmaxf(d1[2], 0.f), fmaxf(d1[3], 0.f)};
      pkfma(acc0a, r0a, ea); pkfma(acc0b, r0b, eb);
      pkfma(acc1a, r1a, ea); pkfma(acc1b, r1b, eb);
    }
  }

  // combine parity waves; write agg into LDS
  if (ih == 1) {
    int cbase = (jt * 64 + l) * 10;
    *reinterpret_cast<f32x2*>(&comb[cbase])     = acc0a;
    *reinterpret_cast<f32x2*>(&comb[cbase + 2]) = acc0b;
    *reinterpret_cast<f32x2*>(&comb[cbase + 4]) = acc1a;
    *reinterpret_cast<f32x2*>(&comb[cbase + 6]) = acc1b;
  }
  __syncthreads();
  if (ih == 0) {
    int cbase = (jt * 64 + l) * 10;
    acc0a += *reinterpret_cast<const f32x2*>(&comb[cbase]);
    acc0b += *reinterpret_cast<const f32x2*>(&comb[cbase + 2]);
    acc1a += *reinterpret_cast<const f32x2*>(&comb[cbase + 4]);
    acc1b += *reinterpret_cast<const f32x2*>(&comb[cbase + 6]);
    float a0v[4] = {acc0a[0], acc0a[1], acc0b[0], acc0b[1]};
    float a1v[4] = {acc1a[0], acc1a[1], acc1b[0], acc1b[1]};
#pragma unroll
    for (int rr = 0; rr < 4; ++rr) {
      int j = jt * 16 + grp * 4 + rr;
      if (j < NV) {
        agg_l[j * 32 + lm]      = a0v[rr];
        agg_l[j * 32 + 16 + lm] = a1v[rr];
      }
    }
  }
  __syncthreads();

  // ======================= PHASE 2: out-MLP =======================
  const int xo = (lm & 7) << 3;

  // aug build (waves 0-3) + stage Wt1sw (all)
  if (tid < 256) {
    int row = tid >> 2, q = tid & 3;
    uint2 u0; uint4 u1;
    if (row < NV) {
      float4 iv = reinterpret_cast<const float4*>(inputs)[(b * NV + row) * 4 + q];
      u0.x = pk2(iv.x, iv.y); u0.y = pk2(iv.z, iv.w);
      f32x4 a0 = *reinterpret_cast<const f32x4*>(&agg_l[row * 32 + q * 8]);
      f32x4 a1 = *reinterpret_cast<const f32x4*>(&agg_l[row * 32 + q * 8 + 4]);
      u1.x = pk2(a0[0], a0[1]); u1.y = pk2(a0[2], a0[3]);
      u1.z = pk2(a1[0], a1[1]); u1.w = pk2(a1[2], a1[3]);
    } else { u0.x = u0.y = 0u; u1.x = u1.y = u1.z = u1.w = 0u; }
    *reinterpret_cast<uint2*>(&aug[row * 72 + q * 4]) = u0;
    *reinterpret_cast<uint4*>(&aug[row * 72 + 16 + q * 8]) = u1;
    uint2 uz; uz.x = 0u; uz.y = 0u;
    *reinterpret_cast<uint2*>(&aug[row * 72 + 48 + q * 4]) = uz;
  }
  {
    const uint4* src = reinterpret_cast<const uint4*>(Wt1sw);
    for (int i2 = tid; i2 < 2048; i2 += 512) reinterpret_cast<uint4*>(WB)[i2] = src[i2];
  }
  __syncthreads();

  const int rowA  = 16 * jt + lm;
  const int kgrp  = grp * 8;
  const int rbase = 16 * jt + grp * 4;
  const int n0    = ih * 8;       // this wave's nt offset

  // fc1: aug[64x64] @ Wt1 -> P1
  f32x4 acc1[8];
#pragma unroll
  for (int nt = 0; nt < 8; ++nt) acc1[nt] = f32x4{0.f, 0.f, 0.f, 0.f};
#pragma unroll
  for (int kc = 0; kc < 2; ++kc) {
    s16x8 af = *reinterpret_cast<const s16x8*>(&aug[rowA * 72 + kc * 32 + kgrp]);
#pragma unroll
    for (int nt = 0; nt < 8; ++nt) {
      int n = lm + 16 * (n0 + nt);
      s16x8 bf = *reinterpret_cast<const s16x8*>(&WB[n * 64 + ((kc * 32 + kgrp) ^ xo)]);
      acc1[nt] = __builtin_amdgcn_mfma_f32_16x16x32_bf16(af, bf, acc1[nt], 0, 0, 0);
    }
  }
#pragma unroll
  for (int nt = 0; nt < 8; ++nt) {
    int n = lm + 16 * (n0 + nt);
    float bias = bo1[n];
#pragma unroll
    for (int rr = 0; rr < 4; ++rr) {
      float v = acc1[nt][rr] + bias; v = v > 0.f ? v : 0.f;
      P1[(rbase + rr) * 264 + n] = f2bf(v);
    }
  }
  __syncthreads();   // WB (Wt1) readers + P1 writers done

  // fc2: P1 @ Wt2 (4 staged chunks)
  f32x4 acc2[8];
#pragma unroll
  for (int nt = 0; nt < 8; ++nt) acc2[nt] = f32x4{0.f, 0.f, 0.f, 0.f};
  for (int c = 0; c < 4; ++c) {
    const uint4* src = reinterpret_cast<const uint4*>(Wt2sw + c * 16384);
    for (int i2 = tid; i2 < 2048; i2 += 512) reinterpret_cast<uint4*>(WB)[i2] = src[i2];
    __syncthreads();
#pragma unroll
    for (int kcl = 0; kcl < 2; ++kcl) {
      int kc = c * 2 + kcl;
      s16x8 af = *reinterpret_cast<const s16x8*>(&P1[rowA * 264 + kc * 32 + kgrp]);
#pragma unroll
      for (int nt = 0; nt < 8; ++nt) {
        int n = lm + 16 * (n0 + nt);
        s16x8 bf = *reinterpret_cast<const s16x8*>(&WB[n * 64 + ((kcl * 32 + kgrp) ^ xo)]);
        acc2[nt] = __builtin_amdgcn_mfma_f32_16x16x32_bf16(af, bf, acc2[nt], 0, 0, 0);
      }
    }
    __syncthreads();
  }
  // epilogue: write pred (f32 out, masked) + P1 bf16 (for mu)
#pragma unroll
  for (int nt = 0; nt < 8; ++nt) {
    int n = lm + 16 * (n0 + nt);
    float bias = bo2[n];
#pragma unroll
    for (int rr = 0; rr < 4; ++rr) {
      int row = rbase + rr;
      float v = acc2[nt][rr] + bias; v = v > 0.f ? v : 0.f;
      if (row < NV) out[PRED_OFF + (b * NV + row) * 256 + n] = v;
      P1[row * 264 + n] = f2bf(v);
    }
  }
  // stage Wtmusw (512 uint4 = one per thread)
  reinterpret_cast<uint4*>(WB)[tid] = reinterpret_cast<const uint4*>(Wtmusw)[tid];
  __syncthreads();

  // mu: pred @ Wtmu (N-half 0 waves only)
  if (ih == 0) {
    f32x4 accm = {0.f, 0.f, 0.f, 0.f};
#pragma unroll
    for (int kc = 0; kc < 8; ++kc) {
      s16x8 af = *reinterpret_cast<const s16x8*>(&P1[rowA * 264 + kc * 32 + kgrp]);
      s16x8 bf = *reinterpret_cast<const s16x8*>(&WB[lm * 256 + ((kc * 32 + kgrp) ^ xo)]);
      accm = __builtin_amdgcn_mfma_f32_16x16x32_bf16(af, bf, accm, 0, 0, 0);
    }
    float bias = bmu[lm];
#pragma unroll
    for (int rr = 0; rr < 4; ++rr) {
      int row = rbase + rr;
      if (row < NV) out[(b * NV + row) * 16 + lm] = accm[rr] + bias;
    }
  }
}

extern "C" void kernel_launch(void* const* d_in, const int* in_sizes, int n_in,
                              void* d_out, int out_size, void* d_ws, size_t ws_size,
                              hipStream_t stream) {
  const float* inputs = (const float*)d_in[0];
  const float* edges  = (const float*)d_in[1];
  const float* w1     = (const float*)d_in[2];
  const float* b1     = (const float*)d_in[3];
  const float* w2     = (const float*)d_in[4];
  const float* b2     = (const float*)d_in[5];
  const float* wo1    = (const float*)d_in[6];
  const float* bo1    = (const float*)d_in[7];
  const float* wo2    = (const float*)d_in[8];
  const float* bo2    = (const float*)d_in[9];
  const float* wmu    = (const float*)d_in[10];
  const float* bmu    = (const float*)d_in[11];
  float* out = (float*)d_out;

  char* ws = (char*)d_ws;
  unsigned short* W2t    = (unsigned short*)(ws + 3276800);
  unsigned short* W1t    = (unsigned short*)(ws + 3282944);
  unsigned short* Wt1sw  = (unsigned short*)(ws + 3295232);
  unsigned short* Wt2sw  = (unsigned short*)(ws + 3328000);
  unsigned short* Wtmusw = (unsigned short*)(ws + 3459072);

  k_tr<<<372, 256, 0, stream>>>(w1, w2, wo1, wo2, wmu, W2t, W1t, Wt1sw, Wt2sw, Wtmusw);
  k_all<<<512, 512, 0, stream>>>(inputs, edges, b1, b2, W1t, W2t,
                                 Wt1sw, bo1, Wt2sw, bo2, Wtmusw, bmu, out);
}